// Round 10
// baseline (24.295 us; speedup 1.0000x reference)
//
#include <hip/hip_runtime.h>
#include <hip/hip_bf16.h>

#define N_NODES 100000
#define D 128
#define N_EDGES 1000000

typedef float v2f __attribute__((ext_vector_type(2)));
typedef float v4f __attribute__((ext_vector_type(4)));
typedef int   v2i __attribute__((ext_vector_type(2)));

// Kernel 1: per-node scores. 8 lanes per node, 8 nodes/wave, one-shot grid.
// z is stream-once -> NON-TEMPORAL loads (don't evict the score table from
// L2; k2's gathers then hit L2 instead of L3/HBM).
// Packed bf16 table: tbl[n] = bf16(z[n].W_src + b) | bf16(z[n].W_dst) << 16
__global__ void __launch_bounds__(256, 4) node_scores_kernel(
    const float* __restrict__ z, const float* __restrict__ W,
    const float* __restrict__ b, unsigned int* __restrict__ tbl) {
  const int tid  = blockIdx.x * blockDim.x + threadIdx.x;
  const int wave = tid >> 6;         // 0..12499 (exact)
  const int lane = threadIdx.x & 63;
  const int sub  = lane >> 3;        // node within wave (0..7)
  const int l8   = lane & 7;         // lane within 8-lane group
  const int node = wave * 8 + sub;   // N_NODES % 8 == 0 -> no guard

  const v4f* zrow = reinterpret_cast<const v4f*>(z + (size_t)node * D);
  const v4f z0 = __builtin_nontemporal_load(zrow + l8);
  const v4f z1 = __builtin_nontemporal_load(zrow + 8 + l8);
  const v4f z2 = __builtin_nontemporal_load(zrow + 16 + l8);
  const v4f z3 = __builtin_nontemporal_load(zrow + 24 + l8);

  const v4f* Wv = reinterpret_cast<const v4f*>(W);   // tiny, keep cached
  const v4f ws0 = Wv[l8],      ws1 = Wv[8 + l8];
  const v4f ws2 = Wv[16 + l8], ws3 = Wv[24 + l8];
  const v4f wd0 = Wv[32 + l8], wd1 = Wv[40 + l8];
  const v4f wd2 = Wv[48 + l8], wd3 = Wv[56 + l8];

  float a = z0.x * ws0.x + z0.y * ws0.y + z0.z * ws0.z + z0.w * ws0.w
          + z1.x * ws1.x + z1.y * ws1.y + z1.z * ws1.z + z1.w * ws1.w
          + z2.x * ws2.x + z2.y * ws2.y + z2.z * ws2.z + z2.w * ws2.w
          + z3.x * ws3.x + z3.y * ws3.y + z3.z * ws3.z + z3.w * ws3.w;
  float c = z0.x * wd0.x + z0.y * wd0.y + z0.z * wd0.z + z0.w * wd0.w
          + z1.x * wd1.x + z1.y * wd1.y + z1.z * wd1.z + z1.w * wd1.w
          + z2.x * wd2.x + z2.y * wd2.y + z2.z * wd2.z + z2.w * wd2.w
          + z3.x * wd3.x + z3.y * wd3.y + z3.z * wd3.z + z3.w * wd3.w;

  #pragma unroll
  for (int off = 4; off >= 1; off >>= 1) {
    a += __shfl_xor(a, off, 64);
    c += __shfl_xor(c, off, 64);
  }
  if (l8 == 0) {
    const unsigned int ha =
        (unsigned int)__bfloat16_as_ushort(__float2bfloat16(a + b[0]));
    const unsigned int hc =
        (unsigned int)__bfloat16_as_ushort(__float2bfloat16(c));
    tbl[node] = ha | (hc << 16);   // normal store: allocate in L2 for k2
  }
}

// Kernel 2: 2 edges/thread; random 4B gathers into the 400KB packed table.
__global__ void __launch_bounds__(256) edge_kernel(
    const int* __restrict__ idx, const unsigned int* __restrict__ tbl,
    float* __restrict__ out) {
  int t = blockIdx.x * blockDim.x + threadIdx.x;
  if (t * 2 >= N_EDGES) return;
  const v2i sv = __builtin_nontemporal_load(
      reinterpret_cast<const v2i*>(idx) + t);            // src row
  const v2i dv = __builtin_nontemporal_load(
      reinterpret_cast<const v2i*>(idx + N_EDGES) + t);  // dst row

  const unsigned int ua0 = tbl[sv.x], ub0 = tbl[dv.x];
  const unsigned int ua1 = tbl[sv.y], ub1 = tbl[dv.y];

  float l0 = __uint_as_float(ua0 << 16) + __uint_as_float(ub0 & 0xFFFF0000u);
  float l1 = __uint_as_float(ua1 << 16) + __uint_as_float(ub1 & 0xFFFF0000u);

  v2f o;
  o.x = 1.0f / (1.0f + __expf(-l0));
  o.y = 1.0f / (1.0f + __expf(-l1));
  __builtin_nontemporal_store(o, reinterpret_cast<v2f*>(out) + t);
}

extern "C" void kernel_launch(void* const* d_in, const int* in_sizes, int n_in,
                              void* d_out, int out_size, void* d_ws, size_t ws_size,
                              hipStream_t stream) {
  const float* z   = (const float*)d_in[0];
  const int*   idx = (const int*)d_in[1];
  const float* W   = (const float*)d_in[2];
  const float* b   = (const float*)d_in[3];
  float* out = (float*)d_out;
  unsigned int* tbl = (unsigned int*)d_ws;   // N_NODES packed bf16 pairs = 400 KB

  node_scores_kernel<<<N_NODES / 32, 256, 0, stream>>>(z, W, b, tbl);

  int blocks2 = (N_EDGES / 2 + 255) / 256;  // 1954
  edge_kernel<<<blocks2, 256, 0, stream>>>(idx, tbl, out);
}